// Round 2
// baseline (112.118 us; speedup 1.0000x reference)
//
#include <hip/hip_runtime.h>
#include <math.h>

#define T_DIM 12

// One thread processes TWO adjacent columns (a = .x/.y, b = .z/.w of a float4).
// Arrays are (T, N, 2) f32 -> row stride in float4 units is N/2.
// All 24 loads are staged into register arrays up front for max MLP.
__global__ __launch_bounds__(256) void ade_traj_kernel(
    const float4* __restrict__ inp,
    const float4* __restrict__ tgt,
    int npairs,          // N/2
    float* __restrict__ ws)   // ws[0] = sum(ade*sel), ws[1] = cnt
{
    const int stride = gridDim.x * blockDim.x;
    float num = 0.0f;
    float cnt = 0.0f;

    for (int i = blockIdx.x * blockDim.x + threadIdx.x; i < npairs; i += stride) {
        // ---- stage ALL loads first (static indexing -> registers) ----
        float4 tv[T_DIM];
        float4 iv[T_DIM];
        #pragma unroll
        for (int t = 0; t < T_DIM; ++t) {
            tv[t] = tgt[t * npairs + i];
        }
        #pragma unroll
        for (int t = 0; t < T_DIM; ++t) {
            iv[t] = inp[t * npairs + i];
        }

        // ---- ADE: mean over t of ||inp - tgt|| per column ----
        float ade_a = 0.0f, ade_b = 0.0f;
        #pragma unroll
        for (int t = 0; t < T_DIM; ++t) {
            float dx = iv[t].x - tv[t].x, dy = iv[t].y - tv[t].y;
            ade_a += sqrtf(dx * dx + dy * dy);
            float dxb = iv[t].z - tv[t].z, dyb = iv[t].w - tv[t].w;
            ade_b += sqrtf(dxb * dxb + dyb * dyb);
        }

        // ---- Menger curvature mask + run-length stats ----
        float run_a = 0.0f, mx_a = 0.0f, sm_a = 0.0f;
        float run_b = 0.0f, mx_b = 0.0f, sm_b = 0.0f;
        #pragma unroll
        for (int t = 2; t < T_DIM; ++t) {
            // column a: points tv[t-2].xy, tv[t-1].xy, tv[t].xy
            {
                float ax = tv[t-2].x, ay = tv[t-2].y;
                float bx = tv[t-1].x, by = tv[t-1].y;
                float cx = tv[t].x,   cy = tv[t].y;
                float area = fabsf(ax * (by - cy) + bx * (cy - ay) + cx * (ay - by));
                float e01x = bx - ax, e01y = by - ay;
                float e12x = cx - bx, e12y = cy - by;
                float e02x = cx - ax, e02y = cy - ay;
                float dist = sqrtf(e01x * e01x + e01y * e01y)
                           * sqrtf(e12x * e12x + e12y * e12y)
                           * sqrtf(e02x * e02x + e02y * e02y);
                float k = 2.0f * area / dist;
                if (__builtin_isnan(k)) k = 0.0f;   // jnp.where(isnan(k),0,k); inf kept
                float m = (fabsf(k) >= 1.0f) ? 1.0f : 0.0f;
                run_a += m;
                mx_a = fmaxf(mx_a, run_a);
                run_a *= m;
                sm_a += m;
            }
            // column b: .zw lanes
            {
                float ax = tv[t-2].z, ay = tv[t-2].w;
                float bx = tv[t-1].z, by = tv[t-1].w;
                float cx = tv[t].z,   cy = tv[t].w;
                float area = fabsf(ax * (by - cy) + bx * (cy - ay) + cx * (ay - by));
                float e01x = bx - ax, e01y = by - ay;
                float e12x = cx - bx, e12y = cy - by;
                float e02x = cx - ax, e02y = cy - ay;
                float dist = sqrtf(e01x * e01x + e01y * e01y)
                           * sqrtf(e12x * e12x + e12y * e12y)
                           * sqrtf(e02x * e02x + e02y * e02y);
                float k = 2.0f * area / dist;
                if (__builtin_isnan(k)) k = 0.0f;
                float m = (fabsf(k) >= 1.0f) ? 1.0f : 0.0f;
                run_b += m;
                mx_b = fmaxf(mx_b, run_b);
                run_b *= m;
                sm_b += m;
            }
        }

        // criteria = (mx >= 3) & (mx < 11) & (sum_mask > 0)
        bool sel_a = (mx_a >= 3.0f) && (mx_a < 11.0f) && (sm_a > 0.0f);
        bool sel_b = (mx_b >= 3.0f) && (mx_b < 11.0f) && (sm_b > 0.0f);
        if (sel_a) { num += ade_a * (1.0f / 12.0f); cnt += 1.0f; }
        if (sel_b) { num += ade_b * (1.0f / 12.0f); cnt += 1.0f; }
    }

    // wave(64) shuffle reduction
    #pragma unroll
    for (int off = 32; off > 0; off >>= 1) {
        num += __shfl_down(num, off, 64);
        cnt += __shfl_down(cnt, off, 64);
    }

    __shared__ float snum[4], scnt[4];
    const int wave = threadIdx.x >> 6;
    const int lane = threadIdx.x & 63;
    if (lane == 0) { snum[wave] = num; scnt[wave] = cnt; }
    __syncthreads();
    if (threadIdx.x == 0) {
        float n = 0.0f, c = 0.0f;
        #pragma unroll
        for (int w = 0; w < 4; ++w) { n += snum[w]; c += scnt[w]; }
        atomicAdd(&ws[0], n);
        atomicAdd(&ws[1], c);
    }
}

__global__ void ade_traj_finalize(const float* __restrict__ ws, float* __restrict__ out)
{
    if (threadIdx.x == 0 && blockIdx.x == 0) {
        float s = ws[0];
        float c = ws[1];
        out[0] = (c > 0.0f) ? (s / fmaxf(c, 1.0f)) : 0.0f;
    }
}

extern "C" void kernel_launch(void* const* d_in, const int* in_sizes, int n_in,
                              void* d_out, int out_size, void* d_ws, size_t ws_size,
                              hipStream_t stream) {
    const float* inp = (const float*)d_in[0];
    const float* tgt = (const float*)d_in[1];
    float* out = (float*)d_out;
    float* ws  = (float*)d_ws;

    // in_sizes[0] = T*N*2
    const int total = in_sizes[0];
    const int N = total / (T_DIM * 2);      // 1,500,000
    const int npairs = N / 2;               // 750,000 (N is even)

    // zero the two accumulators every launch (ws is poisoned once, never restored)
    hipMemsetAsync(ws, 0, 2 * sizeof(float), stream);

    const int block = 256;
    const int grid = (npairs + block - 1) / block;   // ~2930 blocks
    ade_traj_kernel<<<grid, block, 0, stream>>>(
        (const float4*)inp, (const float4*)tgt, npairs, ws);
    ade_traj_finalize<<<1, 64, 0, stream>>>(ws, out);
}